// Round 13
// baseline (135.473 us; speedup 1.0000x reference)
//
#include <hip/hip_runtime.h>
#include <hip/hip_bf16.h>

#define IN_FT 512
#define OUT_FT 128
#define NEG_SLOPE 0.2f
#define SHIFT_C 4.0f    // global score shift: softmax-invariant, guards exp overflow
#define CAP8 768        // per-bin capacity: 8 dsts, mean 512 edges, +11 sigma
#define SEGC 128        // per-dst LDS segment capacity; P(deg>128) ~ 5e-13
#define NBMAX 1280

typedef __attribute__((ext_vector_type(8))) short short8;
typedef __attribute__((ext_vector_type(4))) short short4v;
typedef __attribute__((ext_vector_type(4))) float float4v;

__device__ inline short f2bf_s(float x) {
    __hip_bfloat16 b = __float2bfloat16(x);
    union { __hip_bfloat16 b; short s; } u;
    u.b = b;
    return u.s;
}
__device__ inline float bf2f(short s) {
    union { float f; unsigned u; } u;
    u.u = ((unsigned)(unsigned short)s) << 16;
    return u.f;
}

// ---------------- K1: W_comb = W_gat @ W_fc -> bf16 in MFMA B-fragment order
// (blocks 0..255); blocks >=256 zero the bin cursors. ----------------
__global__ void k_prep(const float* __restrict__ Wg,
                       const float* __restrict__ Wf,
                       short* __restrict__ whf,
                       int* __restrict__ gcur, int nb) {
    if (blockIdx.x >= 256) {
        int i = (blockIdx.x - 256) * 256 + threadIdx.x;
        if (i < nb) gcur[i] = 0;
        return;
    }
    int idx = blockIdx.x * blockDim.x + threadIdx.x;  // 0..65535
    int o = idx >> 9;
    int k = idx & 511;
    float s = 0.f;
#pragma unroll 8
    for (int j = 0; j < OUT_FT; ++j)
        s += Wg[o * OUT_FT + j] * Wf[j * IN_FT + k];
    int t = o >> 4, l15 = o & 15;
    int kc = k >> 5, q = (k >> 3) & 3, jj = k & 7;
    whf[(((kc * 8 + t) * 64) + q * 16 + l15) * 8 + jj] = f2bf_s(s);
}

// ---------------- K2: [0..GB) gemm (LDS-staged A, split-K) + att logits;
//                      [GB..) phase-1 coarse binning of edges (bin = dst>>3). ----
__launch_bounds__(256)
__global__ void k_main(const float* __restrict__ seq,
                       const short8* __restrict__ whf,
                       const float* __restrict__ att_s_v,
                       const float* __restrict__ att_d_v,
                       short* __restrict__ h16,
                       float* __restrict__ a_s,
                       float* __restrict__ a_d,
                       const int* __restrict__ src,
                       const int* __restrict__ dstv,
                       int* __restrict__ gcur,
                       unsigned* __restrict__ bins,
                       int N, int E, int nb, int GB) {
    __shared__ char smem[24576];
    if (blockIdx.x >= GB) {
        // ---- phase-1 binning: this block owns 2048 consecutive edges ----
        int* hist  = (int*)smem;          // [NBMAX]
        int* sbase = hist + NBMAX;        // [NBMAX]
        int* scur  = sbase + NBMAX;       // 3*1280*4 = 15.4 KB
        int e0 = (blockIdx.x - GB) * 2048;
        for (int t = threadIdx.x; t < nb; t += 256) hist[t] = 0;
        __syncthreads();
        int myd[8];
#pragma unroll
        for (int k = 0; k < 8; ++k) {
            int e = e0 + k * 256 + threadIdx.x;
            myd[k] = (e < E) ? dstv[e] : -1;
            if ((unsigned)myd[k] < (unsigned)N) atomicAdd(&hist[myd[k] >> 3], 1);
            else myd[k] = -1;
        }
        __syncthreads();
        for (int t = threadIdx.x; t < nb; t += 256) {
            int c = hist[t];
            sbase[t] = c ? atomicAdd(&gcur[t], c) : 0;
            scur[t] = 0;
        }
        __syncthreads();
#pragma unroll
        for (int k = 0; k < 8; ++k) {
            if (myd[k] >= 0) {
                int e = e0 + k * 256 + threadIdx.x;
                int b = myd[k] >> 3;
                int slot = sbase[b] + atomicAdd(&scur[b], 1);
                if (slot < CAP8) {
                    int s = src[e];
                    if ((unsigned)s >= (unsigned)N) s = 0;
                    bins[(size_t)b * CAP8 + slot] = ((unsigned)s << 3) | (myd[k] & 7);
                }
            }
        }
        return;
    }
    // ---- gemm: tile 16 rows x 128 cols; wave w owns K slice [w*128,(w+1)*128) ----
    short* As = (short*)smem;
    float4v* red = (float4v*)smem;

    int wave = threadIdx.x >> 6;
    int lane = threadIdx.x & 63;
    int l15 = lane & 15, quad = lane >> 4;
    int rows0 = blockIdx.x * 16;

#pragma unroll
    for (int i = 0; i < 8; ++i) {
        int idx = threadIdx.x + 256 * i;
        int r = idx >> 7, c4 = idx & 127;
        int row = rows0 + r;
        int rowc = row < N ? row : N - 1;
        float4 v = *(const float4*)(seq + (size_t)rowc * IN_FT + c4 * 4);
        short4v b;
        b[0] = f2bf_s(v.x); b[1] = f2bf_s(v.y); b[2] = f2bf_s(v.z); b[3] = f2bf_s(v.w);
        int kc = c4 >> 3, q = (c4 >> 1) & 3, half = c4 & 1;
        *(short4v*)(As + (((kc * 4 + q) * 16 + r) * 8 + half * 4)) = b;
    }
    __syncthreads();

    float4v acc[8];
    for (int t = 0; t < 8; ++t) acc[t] = (float4v){0.f, 0.f, 0.f, 0.f};

#pragma unroll
    for (int kk = 0; kk < 4; ++kk) {
        int kc = wave * 4 + kk;
        short8 a = *(const short8*)(As + ((kc * 4 + quad) * 16 + l15) * 8);
        const short8* bhp = whf + (size_t)kc * 512 + lane;
#pragma unroll
        for (int t = 0; t < 8; ++t) {
            short8 bh = bhp[t * 64];
            acc[t] = __builtin_amdgcn_mfma_f32_16x16x32_bf16(a, bh, acc[t], 0, 0, 0);
        }
    }
    __syncthreads();
    if (wave > 0) {
        float4v* base = red + ((wave - 1) * 8) * 64 + lane;
        for (int t = 0; t < 8; ++t) base[t * 64] = acc[t];
    }
    __syncthreads();
    if (wave != 0) return;
    for (int w2 = 0; w2 < 3; ++w2) {
        const float4v* base = red + (w2 * 8) * 64 + lane;
        for (int t = 0; t < 8; ++t) {
            float4v v = base[t * 64];
            acc[t][0] += v[0]; acc[t][1] += v[1]; acc[t][2] += v[2]; acc[t][3] += v[3];
        }
    }
    int rbase = rows0 + quad * 4;
    for (int r = 0; r < 4; ++r) {
        int rr = rbase + r;
        if (rr < N) {
            short* hr = h16 + (size_t)rr * OUT_FT;
            for (int t = 0; t < 8; ++t) hr[t * 16 + l15] = f2bf_s(acc[t][r]);
        }
    }
    float asv[8], adv[8];
    for (int t = 0; t < 8; ++t) {
        asv[t] = att_s_v[t * 16 + l15];
        adv[t] = att_d_v[t * 16 + l15];
    }
    for (int r = 0; r < 4; ++r) {
        float ps = 0.f, pd = 0.f;
        for (int t = 0; t < 8; ++t) {
            float v = acc[t][r];
            ps += v * asv[t];
            pd += v * adv[t];
        }
        for (int m = 1; m < 16; m <<= 1) {
            ps += __shfl_xor(ps, m);
            pd += __shfl_xor(pd, m);
        }
        int rr = rbase + r;
        if (l15 == 0 && rr < N) { a_s[rr] = ps; a_d[rr] = pd; }
    }
}

// ---------------- K3: one block per bin (8 dsts). Single-pass scatter into
// LDS segments (exp once), pad to x16 with p=0 sentinels, then wave-per-dst-
// PAIR aggregation, SOFTWARE-PIPELINED: load batch c+8 while accumulating
// batch c (two 8-deep register sets per dst). No min-waves launch bound —
// R11 showed capping VGPRs here causes scratch spills. ----------------
__launch_bounds__(256)
__global__ void k_agg(const short* __restrict__ h16, const float* __restrict__ a_s,
                      const float* __restrict__ a_d,
                      const int* __restrict__ gcur, const unsigned* __restrict__ bins,
                      const float* __restrict__ gat_bias,
                      const float* __restrict__ bias,
                      const float* __restrict__ prelu_a,
                      float* __restrict__ out, int N) {
    __shared__ int2  seg[8][SEGC];
    __shared__ int   cur8[8], padn[8];
    __shared__ float ads[8];
    int b = blockIdx.x;
    int d0 = b << 3;
    int nd = N - d0; if (nd > 8) nd = 8;
    int tid = threadIdx.x;

    if (tid < 8) {
        cur8[tid] = 0;
        ads[tid] = (tid < nd) ? a_d[d0 + tid] : 0.f;
    }
    __syncthreads();

    int cnt = gcur[b]; if (cnt > CAP8) cnt = CAP8;
    const unsigned* binp = bins + (size_t)b * CAP8;

    // single pass: read packed edge, compute exp once, scatter into segment
    for (int c = tid; c < cnt; c += 256) {
        unsigned pk = binp[c];
        int dl = pk & 7, sv = pk >> 3;
        float ev = a_s[sv] + ads[dl];
        ev = (ev >= 0.f) ? ev : NEG_SLOPE * ev;
        float p = __expf(ev - SHIFT_C);
        int slot = atomicAdd(&cur8[dl], 1);
        if (slot < SEGC) {
            int2 sp; sp.x = sv; sp.y = __float_as_int(p);
            seg[dl][slot] = sp;
        }
    }
    __syncthreads();
    // pad each segment to a multiple of 16 with p=0 sentinels (one barrier)
    if (tid < 128) {
        int dl = tid >> 4, k = tid & 15;
        int n = cur8[dl]; if (n > SEGC) n = SEGC;
        int np = (n + 15) & ~15; if (np > SEGC) np = SEGC;
        if (k == 0) padn[dl] = np;
        if (n + k < np) {
            int2 sp; sp.x = d0; sp.y = 0;   // p=0: no contribution
            seg[dl][n + k] = sp;
        }
    }
    __syncthreads();

    // aggregation: wave w handles dsts dA=d0+w and dB=d0+w+4, pipelined
    int w = tid >> 6, L = tid & 63;
    float b0 = gat_bias[2 * L] + bias[2 * L];
    float b1 = gat_bias[2 * L + 1] + bias[2 * L + 1];
    float pa = prelu_a[0];

    int dA = d0 + w, dB = d0 + w + 4;
    int dAc = dA < N ? dA : d0, dBc = dB < N ? dB : d0;
    float eA = a_s[dAc] + ads[w];
    eA = (eA >= 0.f) ? eA : NEG_SLOPE * eA;
    float p0A = __expf(eA - SHIFT_C);
    float eB = a_s[dBc] + ads[(w + 4) & 7];
    eB = (eB >= 0.f) ? eB : NEG_SLOPE * eB;
    float p0B = __expf(eB - SHIFT_C);
    short2 hA = *(const short2*)(h16 + (size_t)dAc * OUT_FT + 2 * L);
    short2 hB = *(const short2*)(h16 + (size_t)dBc * OUT_FT + 2 * L);
    float accA0 = p0A * bf2f(hA.x), accA1 = p0A * bf2f(hA.y), dsA = 0.f;
    float accB0 = p0B * bf2f(hB.x), accB1 = p0B * bf2f(hB.y), dsB = 0.f;

    const int2* segA = seg[w];
    const int2* segB = seg[w + 4];
    int nA = padn[w], nB = padn[w + 4];   // multiples of 16 (or SEGC)
    int nmax = nA > nB ? nA : nB;

    float pA0[8], pA1[8], pB0[8], pB1[8];
    short2 hA0[8], hA1[8], hB0[8], hB1[8];

#define LOADSEG(SEG, CC, PP, HH)                                          \
    {                                                                     \
        _Pragma("unroll")                                                 \
        for (int j = 0; j < 8; ++j) {                                     \
            int2 sp = (SEG)[(CC) + j];                                    \
            PP[j] = __int_as_float(sp.y);                                 \
            HH[j] = *(const short2*)(h16 + (size_t)sp.x * OUT_FT + 2 * L);\
        }                                                                 \
    }
#define ACCUM(PP, HH, DS, A0, A1)                                         \
    {                                                                     \
        _Pragma("unroll")                                                 \
        for (int j = 0; j < 8; ++j) {                                     \
            DS += PP[j];                                                  \
            A0 += PP[j] * bf2f(HH[j].x);                                  \
            A1 += PP[j] * bf2f(HH[j].y);                                  \
        }                                                                 \
    }

    if (0 < nA) LOADSEG(segA, 0, pA0, hA0)
    if (0 < nB) LOADSEG(segB, 0, pB0, hB0)
    for (int c = 0; c < nmax; c += 16) {
        bool a1 = (c + 8) < nA, b1 = (c + 8) < nB;
        bool a2 = (c + 16) < nA, b2 = (c + 16) < nB;
        if (a1) LOADSEG(segA, c + 8, pA1, hA1)       // prefetch odd batch
        if (b1) LOADSEG(segB, c + 8, pB1, hB1)
        if (c < nA) ACCUM(pA0, hA0, dsA, accA0, accA1)  // consume even batch
        if (c < nB) ACCUM(pB0, hB0, dsB, accB0, accB1)
        if (a2) LOADSEG(segA, c + 16, pA0, hA0)      // prefetch next even
        if (b2) LOADSEG(segB, c + 16, pB0, hB0)
        if (a1) ACCUM(pA1, hA1, dsA, accA0, accA1)      // consume odd batch
        if (b1) ACCUM(pB1, hB1, dsB, accB0, accB1)
    }
#undef LOADSEG
#undef ACCUM

    if (dA < N) {
        float inv = 1.f / (dsA + p0A + 1e-16f);
        float o0 = accA0 * inv + b0;
        float o1 = accA1 * inv + b1;
        o0 = (o0 >= 0.f) ? o0 : pa * o0;
        o1 = (o1 >= 0.f) ? o1 : pa * o1;
        float2 ov; ov.x = o0; ov.y = o1;
        *(float2*)(out + (size_t)dA * OUT_FT + 2 * L) = ov;
    }
    if (dB < N) {
        float inv = 1.f / (dsB + p0B + 1e-16f);
        float o0 = accB0 * inv + b0;
        float o1 = accB1 * inv + b1;
        o0 = (o0 >= 0.f) ? o0 : pa * o0;
        o1 = (o1 >= 0.f) ? o1 : pa * o1;
        float2 ov; ov.x = o0; ov.y = o1;
        *(float2*)(out + (size_t)dB * OUT_FT + 2 * L) = ov;
    }
}

extern "C" void kernel_launch(void* const* d_in, const int* in_sizes, int n_in,
                              void* d_out, int out_size, void* d_ws, size_t ws_size,
                              hipStream_t stream) {
    const float* seq     = (const float*)d_in[0];
    const int*   ei      = (const int*)d_in[1];
    const float* W_fc    = (const float*)d_in[2];
    const float* W_gat   = (const float*)d_in[3];
    const float* att_src = (const float*)d_in[4];
    const float* att_dst = (const float*)d_in[5];
    const float* gat_b   = (const float*)d_in[6];
    const float* bias    = (const float*)d_in[7];
    const float* prelu_a = (const float*)d_in[8];

    int N = in_sizes[0] / IN_FT;
    int E = in_sizes[1] / 2;
    const int* src = ei;
    const int* dst = ei + E;
    int nb = (N + 7) >> 3;            // 1250 bins of 8 dsts

    char* wsb = (char*)d_ws;
    size_t cur = 0;
    auto alloc = [&](size_t bytes) -> void* {
        void* p = (void*)(wsb + cur);
        cur += (bytes + 255) & ~(size_t)255;
        return p;
    };
    short*    h16  = (short*)alloc((size_t)N * OUT_FT * 2);
    float*    a_s  = (float*)alloc((size_t)N * 4);
    float*    a_d  = (float*)alloc((size_t)N * 4);
    int*      gcur = (int*)alloc((size_t)nb * 4);
    unsigned* bins = (unsigned*)alloc((size_t)nb * CAP8 * 4);
    short*    whf  = (short*)alloc((size_t)OUT_FT * IN_FT * 2);

    int GB = (N + 15) / 16;                 // 625 gemm blocks
    int PB = (E + 2047) / 2048;             // 313 binning blocks

    // K1: combined weight in fragment order + zero bin cursors
    k_prep<<<dim3(256 + (nb + 255) / 256), dim3(256), 0, stream>>>(W_gat, W_fc, whf, gcur, nb);
    // K2: gemm + att logits, co-scheduled with coarse edge binning
    k_main<<<dim3(GB + PB), dim3(256), 0, stream>>>(
        seq, (const short8*)whf, att_src, att_dst, h16, a_s, a_d,
        src, dst, gcur, bins, N, E, nb, GB);
    // K3: single-pass LDS-segment sort + pipelined dual-dst aggregation
    k_agg<<<dim3(nb), dim3(256), 0, stream>>>(
        h16, a_s, a_d, gcur, bins, gat_b, bias, prelu_a, (float*)d_out, N);
}

// Round 14
// 127.436 us; speedup vs baseline: 1.0631x; 1.0631x over previous
//
#include <hip/hip_runtime.h>
#include <hip/hip_bf16.h>

#define IN_FT 512
#define OUT_FT 128
#define NEG_SLOPE 0.2f
#define SHIFT_C 4.0f    // global score shift: softmax-invariant, guards exp overflow
#define CAP8 768        // per-bin capacity: 8 dsts, mean 512 edges, +11 sigma
#define SEGC 128        // per-dst LDS segment capacity; P(deg>128) ~ 5e-13
#define NBMAX 1280

typedef __attribute__((ext_vector_type(8))) short short8;
typedef __attribute__((ext_vector_type(4))) short short4v;
typedef __attribute__((ext_vector_type(4))) float float4v;

__device__ inline short f2bf_s(float x) {
    __hip_bfloat16 b = __float2bfloat16(x);
    union { __hip_bfloat16 b; short s; } u;
    u.b = b;
    return u.s;
}
__device__ inline float bf2f(short s) {
    union { float f; unsigned u; } u;
    u.u = ((unsigned)(unsigned short)s) << 16;
    return u.f;
}

// ---------------- K1: W_comb = W_gat @ W_fc -> bf16 in MFMA B-fragment order
// (blocks 0..255); blocks >=256 zero the bin cursors. ----------------
__global__ void k_prep(const float* __restrict__ Wg,
                       const float* __restrict__ Wf,
                       short* __restrict__ whf,
                       int* __restrict__ gcur, int nb) {
    if (blockIdx.x >= 256) {
        int i = (blockIdx.x - 256) * 256 + threadIdx.x;
        if (i < nb) gcur[i] = 0;
        return;
    }
    int idx = blockIdx.x * blockDim.x + threadIdx.x;  // 0..65535
    int o = idx >> 9;
    int k = idx & 511;
    float s = 0.f;
#pragma unroll 8
    for (int j = 0; j < OUT_FT; ++j)
        s += Wg[o * OUT_FT + j] * Wf[j * IN_FT + k];
    int t = o >> 4, l15 = o & 15;
    int kc = k >> 5, q = (k >> 3) & 3, jj = k & 7;
    whf[(((kc * 8 + t) * 64) + q * 16 + l15) * 8 + jj] = f2bf_s(s);
}

// ---------------- K2: [0..GB) gemm (LDS-staged A, split-K) + att logits;
//                      [GB..) phase-1 coarse binning of edges (bin = dst>>3). ----
__launch_bounds__(256)
__global__ void k_main(const float* __restrict__ seq,
                       const short8* __restrict__ whf,
                       const float* __restrict__ att_s_v,
                       const float* __restrict__ att_d_v,
                       short* __restrict__ h16,
                       float* __restrict__ a_s,
                       float* __restrict__ a_d,
                       const int* __restrict__ src,
                       const int* __restrict__ dstv,
                       int* __restrict__ gcur,
                       unsigned* __restrict__ bins,
                       int N, int E, int nb, int GB) {
    __shared__ char smem[24576];
    if (blockIdx.x >= GB) {
        // ---- phase-1 binning: this block owns 2048 consecutive edges ----
        int* hist  = (int*)smem;          // [NBMAX]
        int* sbase = hist + NBMAX;        // [NBMAX]
        int* scur  = sbase + NBMAX;       // 3*1280*4 = 15.4 KB
        int e0 = (blockIdx.x - GB) * 2048;
        for (int t = threadIdx.x; t < nb; t += 256) hist[t] = 0;
        __syncthreads();
        int myd[8];
#pragma unroll
        for (int k = 0; k < 8; ++k) {
            int e = e0 + k * 256 + threadIdx.x;
            myd[k] = (e < E) ? dstv[e] : -1;
            if ((unsigned)myd[k] < (unsigned)N) atomicAdd(&hist[myd[k] >> 3], 1);
            else myd[k] = -1;
        }
        __syncthreads();
        for (int t = threadIdx.x; t < nb; t += 256) {
            int c = hist[t];
            sbase[t] = c ? atomicAdd(&gcur[t], c) : 0;
            scur[t] = 0;
        }
        __syncthreads();
#pragma unroll
        for (int k = 0; k < 8; ++k) {
            if (myd[k] >= 0) {
                int e = e0 + k * 256 + threadIdx.x;
                int b = myd[k] >> 3;
                int slot = sbase[b] + atomicAdd(&scur[b], 1);
                if (slot < CAP8) {
                    int s = src[e];
                    if ((unsigned)s >= (unsigned)N) s = 0;
                    bins[(size_t)b * CAP8 + slot] = ((unsigned)s << 3) | (myd[k] & 7);
                }
            }
        }
        return;
    }
    // ---- gemm: tile 16 rows x 128 cols; wave w owns K slice [w*128,(w+1)*128) ----
    short* As = (short*)smem;
    float4v* red = (float4v*)smem;

    int wave = threadIdx.x >> 6;
    int lane = threadIdx.x & 63;
    int l15 = lane & 15, quad = lane >> 4;
    int rows0 = blockIdx.x * 16;

#pragma unroll
    for (int i = 0; i < 8; ++i) {
        int idx = threadIdx.x + 256 * i;
        int r = idx >> 7, c4 = idx & 127;
        int row = rows0 + r;
        int rowc = row < N ? row : N - 1;
        float4 v = *(const float4*)(seq + (size_t)rowc * IN_FT + c4 * 4);
        short4v b;
        b[0] = f2bf_s(v.x); b[1] = f2bf_s(v.y); b[2] = f2bf_s(v.z); b[3] = f2bf_s(v.w);
        int kc = c4 >> 3, q = (c4 >> 1) & 3, half = c4 & 1;
        *(short4v*)(As + (((kc * 4 + q) * 16 + r) * 8 + half * 4)) = b;
    }
    __syncthreads();

    float4v acc[8];
    for (int t = 0; t < 8; ++t) acc[t] = (float4v){0.f, 0.f, 0.f, 0.f};

#pragma unroll
    for (int kk = 0; kk < 4; ++kk) {
        int kc = wave * 4 + kk;
        short8 a = *(const short8*)(As + ((kc * 4 + quad) * 16 + l15) * 8);
        const short8* bhp = whf + (size_t)kc * 512 + lane;
#pragma unroll
        for (int t = 0; t < 8; ++t) {
            short8 bh = bhp[t * 64];
            acc[t] = __builtin_amdgcn_mfma_f32_16x16x32_bf16(a, bh, acc[t], 0, 0, 0);
        }
    }
    __syncthreads();
    if (wave > 0) {
        float4v* base = red + ((wave - 1) * 8) * 64 + lane;
        for (int t = 0; t < 8; ++t) base[t * 64] = acc[t];
    }
    __syncthreads();
    if (wave != 0) return;
    for (int w2 = 0; w2 < 3; ++w2) {
        const float4v* base = red + (w2 * 8) * 64 + lane;
        for (int t = 0; t < 8; ++t) {
            float4v v = base[t * 64];
            acc[t][0] += v[0]; acc[t][1] += v[1]; acc[t][2] += v[2]; acc[t][3] += v[3];
        }
    }
    int rbase = rows0 + quad * 4;
    for (int r = 0; r < 4; ++r) {
        int rr = rbase + r;
        if (rr < N) {
            short* hr = h16 + (size_t)rr * OUT_FT;
            for (int t = 0; t < 8; ++t) hr[t * 16 + l15] = f2bf_s(acc[t][r]);
        }
    }
    float asv[8], adv[8];
    for (int t = 0; t < 8; ++t) {
        asv[t] = att_s_v[t * 16 + l15];
        adv[t] = att_d_v[t * 16 + l15];
    }
    for (int r = 0; r < 4; ++r) {
        float ps = 0.f, pd = 0.f;
        for (int t = 0; t < 8; ++t) {
            float v = acc[t][r];
            ps += v * asv[t];
            pd += v * adv[t];
        }
        for (int m = 1; m < 16; m <<= 1) {
            ps += __shfl_xor(ps, m);
            pd += __shfl_xor(pd, m);
        }
        int rr = rbase + r;
        if (l15 == 0 && rr < N) { a_s[rr] = ps; a_d[rr] = pd; }
    }
}

// ---------------- K3: one block per bin (8 dsts), 512 threads = 8 waves,
// ONE WAVE PER DST (TLP for latency hiding: ~10 waves/SIMD). Single-pass
// scatter into LDS segments (exp once), pad to x8 sentinels, then the
// R10-proven 8-deep batched register accumulation, single-dst. ----------------
__launch_bounds__(512)
__global__ void k_agg(const short* __restrict__ h16, const float* __restrict__ a_s,
                      const float* __restrict__ a_d,
                      const int* __restrict__ gcur, const unsigned* __restrict__ bins,
                      const float* __restrict__ gat_bias,
                      const float* __restrict__ bias,
                      const float* __restrict__ prelu_a,
                      float* __restrict__ out, int N) {
    __shared__ int2  seg[8][SEGC];
    __shared__ int   cur8[8], padn[8];
    __shared__ float ads[8];
    int b = blockIdx.x;
    int d0 = b << 3;
    int nd = N - d0; if (nd > 8) nd = 8;
    int tid = threadIdx.x;

    if (tid < 8) {
        cur8[tid] = 0;
        ads[tid] = (tid < nd) ? a_d[d0 + tid] : 0.f;
    }
    __syncthreads();

    int cnt = gcur[b]; if (cnt > CAP8) cnt = CAP8;
    const unsigned* binp = bins + (size_t)b * CAP8;

    // single pass: read packed edge, compute exp once, scatter into segment
    for (int c = tid; c < cnt; c += 512) {
        unsigned pk = binp[c];
        int dl = pk & 7, sv = pk >> 3;
        float ev = a_s[sv] + ads[dl];
        ev = (ev >= 0.f) ? ev : NEG_SLOPE * ev;
        float p = __expf(ev - SHIFT_C);
        int slot = atomicAdd(&cur8[dl], 1);
        if (slot < SEGC) {
            int2 sp; sp.x = sv; sp.y = __float_as_int(p);
            seg[dl][slot] = sp;
        }
    }
    __syncthreads();
    // pad each segment to a multiple of 8 with p=0 sentinels
    if (tid < 64) {
        int dl = tid >> 3, k = tid & 7;
        int n = cur8[dl]; if (n > SEGC) n = SEGC;
        int np = (n + 7) & ~7; if (np > SEGC) np = SEGC;
        if (k == 0) padn[dl] = np;
        if (n + k < np) {
            int2 sp; sp.x = d0; sp.y = 0;   // p=0: no contribution
            seg[dl][n + k] = sp;
        }
    }
    __syncthreads();

    // aggregation: wave w owns dst d0+w exclusively
    int w = tid >> 6, L = tid & 63;
    int d = d0 + w;
    if (d >= N) return;                     // wave-uniform; no barriers after

    float b0 = gat_bias[2 * L] + bias[2 * L];
    float b1 = gat_bias[2 * L + 1] + bias[2 * L + 1];
    float pa = prelu_a[0];

    float e0 = a_s[d] + ads[w];
    e0 = (e0 >= 0.f) ? e0 : NEG_SLOPE * e0;
    float p0 = __expf(e0 - SHIFT_C);
    short2 hs0 = *(const short2*)(h16 + (size_t)d * OUT_FT + 2 * L);
    float acc0 = p0 * bf2f(hs0.x), acc1 = p0 * bf2f(hs0.y), dsum = 0.f;

    const int2* sg = seg[w];
    int n = padn[w];                        // multiple of 8 (or SEGC)
    for (int c = 0; c < n; c += 8) {
        float pp[8]; short2 hh[8];
#pragma unroll
        for (int j = 0; j < 8; ++j) {
            int2 sp = sg[c + j];                         // LDS broadcast
            pp[j] = __int_as_float(sp.y);
            hh[j] = *(const short2*)(h16 + (size_t)sp.x * OUT_FT + 2 * L);
        }
#pragma unroll
        for (int j = 0; j < 8; ++j) {
            dsum += pp[j];
            acc0 += pp[j] * bf2f(hh[j].x);
            acc1 += pp[j] * bf2f(hh[j].y);
        }
    }
    float inv = 1.f / (dsum + p0 + 1e-16f);
    float o0 = acc0 * inv + b0;
    float o1 = acc1 * inv + b1;
    o0 = (o0 >= 0.f) ? o0 : pa * o0;
    o1 = (o1 >= 0.f) ? o1 : pa * o1;
    float2 ov; ov.x = o0; ov.y = o1;
    *(float2*)(out + (size_t)d * OUT_FT + 2 * L) = ov;
}

extern "C" void kernel_launch(void* const* d_in, const int* in_sizes, int n_in,
                              void* d_out, int out_size, void* d_ws, size_t ws_size,
                              hipStream_t stream) {
    const float* seq     = (const float*)d_in[0];
    const int*   ei      = (const int*)d_in[1];
    const float* W_fc    = (const float*)d_in[2];
    const float* W_gat   = (const float*)d_in[3];
    const float* att_src = (const float*)d_in[4];
    const float* att_dst = (const float*)d_in[5];
    const float* gat_b   = (const float*)d_in[6];
    const float* bias    = (const float*)d_in[7];
    const float* prelu_a = (const float*)d_in[8];

    int N = in_sizes[0] / IN_FT;
    int E = in_sizes[1] / 2;
    const int* src = ei;
    const int* dst = ei + E;
    int nb = (N + 7) >> 3;            // 1250 bins of 8 dsts

    char* wsb = (char*)d_ws;
    size_t cur = 0;
    auto alloc = [&](size_t bytes) -> void* {
        void* p = (void*)(wsb + cur);
        cur += (bytes + 255) & ~(size_t)255;
        return p;
    };
    short*    h16  = (short*)alloc((size_t)N * OUT_FT * 2);
    float*    a_s  = (float*)alloc((size_t)N * 4);
    float*    a_d  = (float*)alloc((size_t)N * 4);
    int*      gcur = (int*)alloc((size_t)nb * 4);
    unsigned* bins = (unsigned*)alloc((size_t)nb * CAP8 * 4);
    short*    whf  = (short*)alloc((size_t)OUT_FT * IN_FT * 2);

    int GB = (N + 15) / 16;                 // 625 gemm blocks
    int PB = (E + 2047) / 2048;             // 313 binning blocks

    // K1: combined weight in fragment order + zero bin cursors
    k_prep<<<dim3(256 + (nb + 255) / 256), dim3(256), 0, stream>>>(W_gat, W_fc, whf, gcur, nb);
    // K2: gemm + att logits, co-scheduled with coarse edge binning
    k_main<<<dim3(GB + PB), dim3(256), 0, stream>>>(
        seq, (const short8*)whf, att_src, att_dst, h16, a_s, a_d,
        src, dst, gcur, bins, N, E, nb, GB);
    // K3: 8 waves/block, one wave per dst — TLP-based latency hiding
    k_agg<<<dim3(nb), dim3(512), 0, stream>>>(
        h16, a_s, a_d, gcur, bins, gat_b, bias, prelu_a, (float*)d_out, N);
}